// Round 1
// baseline (384.167 us; speedup 1.0000x reference)
//
#include <hip/hip_runtime.h>

// Problem constants
#define NN    8192   // nodes
#define BB    32     // batch
#define EMB   16     // embed dim
#define HID   64     // hidden
#define INPC  2      // input channels
#define VCOLS 64     // = BB*INPC, columns of V

#define TN 32        // rows per block (k_prop)
#define TM 64        // m-tile
#define MS 2         // m-range splits

// ---------------------------------------------------------------------------
// K1: V[m][j] = x[b=j>>1][m][c=j&1]   (transpose x [B,N,2] -> V [N,64])
// ---------------------------------------------------------------------------
__global__ void k_build_v(const float* __restrict__ x, float* __restrict__ V) {
    int t = blockIdx.x * blockDim.x + threadIdx.x;   // 0 .. N*64-1
    int m = t >> 6;
    int j = t & 63;
    V[t] = x[(j >> 1) * (NN * INPC) + m * INPC + (j & 1)];
}

// ---------------------------------------------------------------------------
// K2: flash-style propagation.
// Block = 256 threads, owns TN=32 rows, processes NN/MS m's (blockIdx.y half).
// Outputs unnormalized ynum_half[N][64] and denom_half[N].
// ---------------------------------------------------------------------------
__launch_bounds__(256, 2)
__global__ void k_prop(const float* __restrict__ adj, const float* __restrict__ V,
                       float* __restrict__ ynum_base, float* __restrict__ den_base) {
    __shared__ float am[TM][EMB];        // 4 KB
    __shared__ float Vs[TM][VCOLS];      // 16 KB
    __shared__ float W[TN][TM + 1];      // 8.3 KB (padded: conflict-free col reads)
    __shared__ float red[256];

    const int t  = threadIdx.x;
    const int tn = t & 31;
    const int jg = t >> 5;               // 0..7, owns 8 output columns
    const int n0 = blockIdx.x * TN;
    const int n  = n0 + tn;

    float* __restrict__ yh = ynum_base + (size_t)blockIdx.y * (NN * VCOLS);
    float* __restrict__ dh = den_base  + (size_t)blockIdx.y * NN;

    const int m_begin = blockIdx.y * (NN / MS);
    const int m_end   = m_begin + (NN / MS);

    // my row of adj in registers
    float an[EMB];
#pragma unroll
    for (int d = 0; d < EMB; ++d) an[d] = adj[n * EMB + d];

    float acc[8] = {0.f, 0.f, 0.f, 0.f, 0.f, 0.f, 0.f, 0.f};
    float dsum = 0.f;
    const int j0 = jg * 8;

    for (int m0 = m_begin; m0 < m_end; m0 += TM) {
        // stage adj m-tile: 64 rows x 16 floats = 256 float4, one per thread
        ((float4*)am)[t] = ((const float4*)(adj + m0 * EMB))[t];
        // stage V tile: 64x64 floats = 1024 float4, 4 per thread
        {
            const float4* src = (const float4*)(V + (size_t)m0 * VCOLS);
#pragma unroll
            for (int q = 0; q < 4; ++q)
                ((float4*)Vs)[t + 256 * q] = src[t + 256 * q];
        }
        __syncthreads();

        // Phase A: scores -> W[tn][tm] = exp(relu(dot(an, am[tm])))
#pragma unroll
        for (int s = 0; s < 8; ++s) {
            int tm = jg * 8 + s;         // lanes 0-31 share tm -> am broadcast
            float sc = 0.f;
#pragma unroll
            for (int d = 0; d < EMB; ++d) sc += an[d] * am[tm][d];
            float w = __expf(fmaxf(sc, 0.f));
            W[tn][tm] = w;
            dsum += w;
        }
        __syncthreads();

        // Phase B: acc[j] += W[tn][m] * Vs[m][j0+j]
#pragma unroll 4
        for (int m = 0; m < TM; ++m) {
            float w = W[tn][m];
            float4 va = *(const float4*)&Vs[m][j0];
            float4 vb = *(const float4*)&Vs[m][j0 + 4];
            acc[0] += w * va.x;  acc[1] += w * va.y;
            acc[2] += w * va.z;  acc[3] += w * va.w;
            acc[4] += w * vb.x;  acc[5] += w * vb.y;
            acc[6] += w * vb.z;  acc[7] += w * vb.w;
        }
        __syncthreads();
    }

    // write unnormalized accumulators
#pragma unroll
    for (int jj = 0; jj < 8; ++jj)
        yh[(size_t)n * VCOLS + j0 + jj] = acc[jj];

    // reduce dsum across the 8 threads sharing tn
    red[t] = dsum;
    __syncthreads();
    if (t < TN) {
        float s = 0.f;
#pragma unroll
        for (int k = 0; k < 8; ++k) s += red[t + 32 * k];
        dh[n0 + t] = s;
    }
}

// ---------------------------------------------------------------------------
// K3: epilogue. Block per node n (64 threads = o).
// out[b,n,o] = x[b,n,0]*W0[0,o] + x[b,n,1]*W0[1,o]
//            + y[n,2b]*W1[0,o]  + y[n,2b+1]*W1[1,o] + bias[o]
// where Wk[i,o] = sum_d adj[n,d]*wp[d,k,i,o], bias = adj[n,:] @ bp,
//       y[n,j] = (y0[n,j]+y1[n,j]) / (d0[n]+d1[n])
// ---------------------------------------------------------------------------
__global__ void k_epi(const float* __restrict__ adj, const float* __restrict__ wp,
                      const float* __restrict__ bp, const float* __restrict__ x,
                      const float* __restrict__ y0, const float* __restrict__ y1,
                      const float* __restrict__ d0, const float* __restrict__ d1,
                      float* __restrict__ out) {
    const int n = blockIdx.x;
    const int o = threadIdx.x;   // 0..63
    __shared__ float xl[VCOLS];
    __shared__ float yl[VCOLS];

    float an[EMB];
#pragma unroll
    for (int d = 0; d < EMB; ++d) an[d] = adj[n * EMB + d];  // uniform -> s_load

    float W00 = 0.f, W01 = 0.f, W10 = 0.f, W11 = 0.f, bias = 0.f;
#pragma unroll
    for (int d = 0; d < EMB; ++d) {
        float a = an[d];
        W00 += a * wp[((d * 2 + 0) * 2 + 0) * HID + o];
        W01 += a * wp[((d * 2 + 0) * 2 + 1) * HID + o];
        W10 += a * wp[((d * 2 + 1) * 2 + 0) * HID + o];
        W11 += a * wp[((d * 2 + 1) * 2 + 1) * HID + o];
        bias += a * bp[d * HID + o];
    }

    float rden = 1.f / (d0[n] + d1[n]);
    yl[o] = (y0[(size_t)n * VCOLS + o] + y1[(size_t)n * VCOLS + o]) * rden;
    xl[o] = x[(o >> 1) * (NN * INPC) + n * INPC + (o & 1)];
    __syncthreads();

#pragma unroll 4
    for (int b = 0; b < BB; ++b) {
        float v = xl[2 * b] * W00 + xl[2 * b + 1] * W01
                + yl[2 * b] * W10 + yl[2 * b + 1] * W11 + bias;
        out[((size_t)b * NN + n) * HID + o] = v;
    }
}

// ---------------------------------------------------------------------------
extern "C" void kernel_launch(void* const* d_in, const int* in_sizes, int n_in,
                              void* d_out, int out_size, void* d_ws, size_t ws_size,
                              hipStream_t stream) {
    const float* x   = (const float*)d_in[0];   // [32, 8192, 2]
    const float* adj = (const float*)d_in[1];   // [8192, 16]
    const float* wp  = (const float*)d_in[2];   // [16, 2, 2, 64]
    const float* bp  = (const float*)d_in[3];   // [16, 64]
    float* out = (float*)d_out;                 // [32, 8192, 64]

    float* w = (float*)d_ws;
    float* V    = w;                             // N*64
    float* ynum = w + (size_t)NN * VCOLS;        // MS * N*64
    float* den  = w + (size_t)(1 + MS) * NN * VCOLS;  // MS * N
    float* y0 = ynum;
    float* y1 = ynum + (size_t)NN * VCOLS;
    float* d0 = den;
    float* d1 = den + NN;

    // K1: transpose x -> V
    k_build_v<<<(NN * VCOLS) / 256, 256, 0, stream>>>(x, V);
    // K2: propagation (flash-style), deterministic 2-way m-split
    k_prop<<<dim3(NN / TN, MS), 256, 0, stream>>>(adj, V, ynum, den);
    // K3: epilogue
    k_epi<<<NN, 64, 0, stream>>>(adj, wp, bp, x, y0, y1, d0, d1, out);
}

// Round 2
// 130.216 us; speedup vs baseline: 2.9502x; 2.9502x over previous
//
#include <hip/hip_runtime.h>

#define NN 8192
#define BB 32
#define EMB 16
#define HID 64
#define VCOLS 64
#define MS 16          // m-range splits (accumulated via atomics)
#define TN 128         // n-rows per block
#define TM 64          // m per tile
#define VT_PITCH 8192  // bf16 elems per VT row

typedef __attribute__((ext_vector_type(8))) short bf16x8;
typedef __attribute__((ext_vector_type(4))) float f32x4;

static __device__ inline short f2b(float f) {
    union { float f; unsigned u; } v; v.f = f;
    unsigned r = (v.u + 0x7fffu + ((v.u >> 16) & 1u)) >> 16;
    return (short)r;
}

// ---------------------------------------------------------------------------
// K1: build bf16 VT[j][m] = x[b=j>>1][m][c=j&1]  and  adjB[n][d] = bf16(adj)
// grid: 512 blocks (VT) + 128 blocks (adjB), 256 threads
// ---------------------------------------------------------------------------
__global__ void k_build(const float* __restrict__ x, const float* __restrict__ adj,
                        short* __restrict__ VT, short* __restrict__ adjB) {
    int t = threadIdx.x;
    if (blockIdx.x < 512) {
        int idx = blockIdx.x * 256 + t;          // 0 .. 131071
        int b = idx >> 12;                        // 0..31
        int m = (idx & 4095) * 2;                 // even m
        float4 xx = *(const float4*)(x + (size_t)b * NN * 2 + 2 * m);
        unsigned u0 = (unsigned short)f2b(xx.x) | ((unsigned)(unsigned short)f2b(xx.z) << 16);
        unsigned u1 = (unsigned short)f2b(xx.y) | ((unsigned)(unsigned short)f2b(xx.w) << 16);
        *(unsigned*)(VT + (size_t)(2 * b) * VT_PITCH + m) = u0;
        *(unsigned*)(VT + (size_t)(2 * b + 1) * VT_PITCH + m) = u1;
    } else {
        int idx = (blockIdx.x - 512) * 256 + t;   // 0 .. 32767
        float4 aa = *(const float4*)(adj + (size_t)idx * 4);
        unsigned u0 = (unsigned short)f2b(aa.x) | ((unsigned)(unsigned short)f2b(aa.y) << 16);
        unsigned u1 = (unsigned short)f2b(aa.z) | ((unsigned)(unsigned short)f2b(aa.w) << 16);
        uint2 uu; uu.x = u0; uu.y = u1;
        *(uint2*)(adjB + (size_t)idx * 4) = uu;
    }
}

// ---------------------------------------------------------------------------
// K2: MFMA flash propagation. Block = 256 thr (4 waves), TN=128 rows,
// m-chunk = NN/MS, tiles of TM=64. No inter-wave deps in the K-loop except
// LDS staging barriers. Unnormalized ynum/den accumulated via atomics.
// ---------------------------------------------------------------------------
__launch_bounds__(256, 4)
__global__ void k_prop(const short* __restrict__ adjB, const short* __restrict__ VT,
                       float* __restrict__ ynum, float* __restrict__ den) {
    __shared__ char smraw[128 * 68 * 4];     // 34816 B, unioned
    short* adjT = (short*)smraw;              // [64][16]  (2 KB, granule-xor swizz)
    short* vt   = (short*)(smraw + 2048);     // [64][72]  (9.2 KB, granule-rot swizz)
    float* OL   = (float*)smraw;              // [128][68] fp32 (post-loop)

    const int t = threadIdx.x;
    const int wv = t >> 6;
    const int lane = t & 63;
    const int l = lane & 15;
    const int q = lane >> 4;
    const int n0 = blockIdx.x * TN;
    const int mbeg = blockIdx.y * (NN / MS);

    // score B-fragments (adj cols for this wave's 32 n-rows), k>=16 zeroed
    bf16x8 Bn[2];
    bf16x8 zv = {0, 0, 0, 0, 0, 0, 0, 0};
#pragma unroll
    for (int s = 0; s < 2; ++s) {
        const short* src = adjB + (size_t)(n0 + 32 * wv + 16 * s + l) * EMB + (q & 1) * 8;
        bf16x8 v = *(const bf16x8*)src;
        Bn[s] = (q < 2) ? v : zv;
    }

    f32x4 acc[4][2];
#pragma unroll
    for (int u = 0; u < 4; ++u)
#pragma unroll
        for (int s = 0; s < 2; ++s) {
            acc[u][s][0] = 0.f; acc[u][s][1] = 0.f; acc[u][s][2] = 0.f; acc[u][s][3] = 0.f;
        }
    float dsum[2] = {0.f, 0.f};
    const int mrow_b = 8 * (l >> 2) + (l & 3);   // permuted-row base

    for (int m0 = mbeg; m0 < mbeg + (NN / MS); m0 += TM) {
        __syncthreads();
        // stage adj m-tile (64x16 bf16 = 2 KB), granule xor-swizzle
        if (t < 128) {
            int row = t >> 1, g = t & 1;
            *(bf16x8*)(adjT + row * 16 + ((g ^ (row & 1)) * 8)) =
                *(const bf16x8*)(adjB + (size_t)m0 * EMB + t * 8);
        }
        // stage VT tile (64x64 bf16 = 8 KB), pitch 72, granule rotate-swizzle
#pragma unroll
        for (int cc = 0; cc < 2; ++cc) {
            int id = t * 2 + cc;
            int j = id >> 3;
            int g = id & 7;
            int gs = (g + (j & 7)) & 7;
            *(bf16x8*)(vt + j * 72 + gs * 8) =
                *(const bf16x8*)(VT + (size_t)j * VT_PITCH + m0 + g * 8);
        }
        __syncthreads();

#pragma unroll
        for (int c = 0; c < 2; ++c) {
            short pe0[8], pe1[8];
#pragma unroll
            for (int h = 0; h < 2; ++h) {
                int mrow = mrow_b + 32 * c + 4 * h;
                bf16x8 Af = *(const bf16x8*)(adjT + mrow * 16 + (((q & 1) ^ (mrow & 1)) * 8));
                f32x4 z = {0.f, 0.f, 0.f, 0.f};
                f32x4 S0 = __builtin_amdgcn_mfma_f32_16x16x32_bf16(Af, Bn[0], z, 0, 0, 0);
                f32x4 S1 = __builtin_amdgcn_mfma_f32_16x16x32_bf16(Af, Bn[1], z, 0, 0, 0);
#pragma unroll
                for (int r = 0; r < 4; ++r) {
                    float p0 = __expf(fmaxf(S0[r], 0.f));
                    float p1 = __expf(fmaxf(S1[r], 0.f));
                    dsum[0] += p0; dsum[1] += p1;
                    pe0[4 * h + r] = f2b(p0);
                    pe1[4 * h + r] = f2b(p1);
                }
            }
            bf16x8 pf0 = {pe0[0], pe0[1], pe0[2], pe0[3], pe0[4], pe0[5], pe0[6], pe0[7]};
            bf16x8 pf1 = {pe1[0], pe1[1], pe1[2], pe1[3], pe1[4], pe1[5], pe1[6], pe1[7]};
#pragma unroll
            for (int u = 0; u < 4; ++u) {
                int row = 16 * u + l;
                int gs = ((4 * c + q) + (l & 7)) & 7;
                bf16x8 Vf = *(const bf16x8*)(vt + row * 72 + gs * 8);
                acc[u][0] = __builtin_amdgcn_mfma_f32_16x16x32_bf16(Vf, pf0, acc[u][0], 0, 0, 0);
                acc[u][1] = __builtin_amdgcn_mfma_f32_16x16x32_bf16(Vf, pf1, acc[u][1], 0, 0, 0);
            }
        }
    }

    // denominator: reduce over the 4 quads (cols are lane&15 for every call)
#pragma unroll
    for (int s = 0; s < 2; ++s) {
        float d = dsum[s];
        d += __shfl_xor(d, 16);
        d += __shfl_xor(d, 32);
        if (q == 0) atomicAdd(den + (n0 + 32 * wv + 16 * s + l), d);
    }

    // transpose O^T[j][n] -> OL[n][j] in LDS, then coalesced atomics
    __syncthreads();
#pragma unroll
    for (int u = 0; u < 4; ++u)
#pragma unroll
        for (int s = 0; s < 2; ++s)
#pragma unroll
            for (int r = 0; r < 4; ++r)
                OL[(32 * wv + 16 * s + l) * 68 + 16 * u + 4 * q + r] = acc[u][s][r];
    __syncthreads();
    for (int rr = 0; rr < 32; ++rr) {
        int nloc = 32 * wv + rr;
        atomicAdd(ynum + (size_t)(n0 + nloc) * 64 + lane, OL[nloc * 68 + lane]);
    }
}

// ---------------------------------------------------------------------------
// K3: epilogue (identity term + node-adaptive weights/bias + normalize)
// ---------------------------------------------------------------------------
__global__ void k_epi(const float* __restrict__ adj, const float* __restrict__ wp,
                      const float* __restrict__ bp, const float* __restrict__ x,
                      const float* __restrict__ ynum, const float* __restrict__ den,
                      float* __restrict__ out) {
    const int n = blockIdx.x;
    const int o = threadIdx.x;   // 0..63
    __shared__ float xl[VCOLS];
    __shared__ float yl[VCOLS];

    float an[EMB];
#pragma unroll
    for (int d = 0; d < EMB; ++d) an[d] = adj[n * EMB + d];

    float W00 = 0.f, W01 = 0.f, W10 = 0.f, W11 = 0.f, bias = 0.f;
#pragma unroll
    for (int d = 0; d < EMB; ++d) {
        float a = an[d];
        W00 += a * wp[((d * 2 + 0) * 2 + 0) * HID + o];
        W01 += a * wp[((d * 2 + 0) * 2 + 1) * HID + o];
        W10 += a * wp[((d * 2 + 1) * 2 + 0) * HID + o];
        W11 += a * wp[((d * 2 + 1) * 2 + 1) * HID + o];
        bias += a * bp[d * HID + o];
    }

    float rden = 1.f / den[n];
    yl[o] = ynum[(size_t)n * VCOLS + o] * rden;
    xl[o] = x[(o >> 1) * (NN * 2) + n * 2 + (o & 1)];
    __syncthreads();

#pragma unroll 4
    for (int b = 0; b < BB; ++b) {
        float v = xl[2 * b] * W00 + xl[2 * b + 1] * W01
                + yl[2 * b] * W10 + yl[2 * b + 1] * W11 + bias;
        out[((size_t)b * NN + n) * HID + o] = v;
    }
}

// ---------------------------------------------------------------------------
extern "C" void kernel_launch(void* const* d_in, const int* in_sizes, int n_in,
                              void* d_out, int out_size, void* d_ws, size_t ws_size,
                              hipStream_t stream) {
    const float* x   = (const float*)d_in[0];   // [32, 8192, 2]
    const float* adj = (const float*)d_in[1];   // [8192, 16]
    const float* wp  = (const float*)d_in[2];   // [16, 2, 2, 64]
    const float* bp  = (const float*)d_in[3];   // [16, 64]
    float* out = (float*)d_out;                 // [32, 8192, 64]

    char* w = (char*)d_ws;
    short* VT   = (short*)w;                                    // 1 MB
    short* adjB = (short*)(w + (size_t)64 * VT_PITCH * 2);      // 256 KB
    float* ynum = (float*)(w + (size_t)64 * VT_PITCH * 2 + (size_t)NN * EMB * 2);  // 2 MB
    float* den  = ynum + (size_t)NN * VCOLS;                    // 32 KB

    // zero the accumulators (ynum + den are contiguous)
    hipMemsetAsync(ynum, 0, ((size_t)NN * VCOLS + NN) * sizeof(float), stream);
    // bf16 operand prep
    k_build<<<640, 256, 0, stream>>>(x, adj, VT, adjB);
    // MFMA propagation
    k_prop<<<dim3(NN / TN, MS), 256, 0, stream>>>(adjB, VT, ynum, den);
    // epilogue
    k_epi<<<NN, 64, 0, stream>>>(adj, wp, bp, x, ynum, den, out);
}